// Round 2
// baseline (126.100 us; speedup 1.0000x reference)
//
#include <hip/hip_runtime.h>

#define SIGMA 0.5f
#define BB 32
#define NVV 6890
#define NFF 13776
#define MAXC 8
#define NCC (NFF * MAXC)                 // 110208 pairs per batch

// fused kernel geometry: one block per (batch, slot); 8 slots per batch.
#define SLOTS 8
#define PAIRS_PER_SLOT (NCC / SLOTS)     // 13776 exactly
#define QHALF (PAIRS_PER_SLOT / 4)       // 3444 exactly (4 pairs per thread-iter)
#define THREADS 1024
#define NBLOCK (BB * SLOTS)              // 256 blocks == 256 CUs

typedef int       v4i __attribute__((ext_vector_type(4)));
typedef _Float16  h4  __attribute__((ext_vector_type(4)));

__device__ __forceinline__ float3 loadv3(const float* __restrict__ p) {
    return make_float3(p[0], p[1], p[2]);
}

// one-sided conic penetration: query tri q0..q2 in field of tri a0..a2 (f32 math)
__device__ __forceinline__ float conePen(float3 a0, float3 a1, float3 a2,
                                         float3 q0, float3 q1, float3 q2) {
    const float third = 1.0f / 3.0f;
    float cx = (a0.x + a1.x + a2.x) * third;
    float cy = (a0.y + a1.y + a2.y) * third;
    float cz = (a0.z + a1.z + a2.z) * third;
    float e1x = a1.x - a0.x, e1y = a1.y - a0.y, e1z = a1.z - a0.z;
    float e2x = a2.x - a0.x, e2y = a2.y - a0.y, e2z = a2.z - a0.z;
    float nx = e1y * e2z - e1z * e2y;
    float ny = e1z * e2x - e1x * e2z;
    float nz = e1x * e2y - e1y * e2x;
    float inv = 1.0f / (sqrtf(nx * nx + ny * ny + nz * nz) + 1e-8f);
    nx *= inv; ny *= inv; nz *= inv;
    float3 q[3] = {q0, q1, q2};
    float pen = 0.0f;
#pragma unroll
    for (int v = 0; v < 3; ++v) {
        float dx = q[v].x - cx, dy = q[v].y - cy, dz = q[v].z - cz;
        float h = dx * nx + dy * ny + dz * nz;
        float r = sqrtf(dx * dx + dy * dy + dz * dz);
        float phi = fmaxf(SIGMA - r, 0.0f);
        pen += (h < 0.0f) ? phi * h * h : 0.0f;
    }
    return pen;
}

// load one fp16 vertex by PRE-SHIFTED byte offset (one ds_read_b64, base folds to imm)
__device__ __forceinline__ float3 ldsVertB(const h4* __restrict__ sv, unsigned int boff) {
    h4 h = *(const h4*)((const char*)sv + boff);
    return make_float3((float)h.x, (float)h.y, (float)h.z);
}

// symmetric penetration for one collision pair, all gathers from LDS
__device__ __forceinline__ float pairPen(const h4* __restrict__ sv,
                                         const unsigned int*   __restrict__ f01,
                                         const unsigned short* __restrict__ f2,
                                         int r, int it) {
    if (r < 0) return 0.0f;               // padding slot
    const int g = it < 0 ? 0 : it;        // reference clamps with max(idx,0)
    unsigned int wa = f01[r];
    unsigned int wb = f01[g];
    unsigned int oa2 = f2[r];             // already byte offsets (idx*8)
    unsigned int ob2 = f2[g];
    float3 A0 = ldsVertB(sv, wa & 0xFFFFu);
    float3 A1 = ldsVertB(sv, wa >> 16);
    float3 A2 = ldsVertB(sv, oa2);
    float3 B0 = ldsVertB(sv, wb & 0xFFFFu);
    float3 B1 = ldsVertB(sv, wb >> 16);
    float3 B2 = ldsVertB(sv, ob2);
    return conePen(A0, A1, A2, B0, B1, B2) + conePen(B0, B1, B2, A0, A1, A2);
}

// ---------------- fused: stage batch verts+faces in LDS, eval pairs --------
__global__ __launch_bounds__(THREADS) void fused_kernel(
    const float* __restrict__ vertices,   // [B, NV, 3]
    const int*   __restrict__ faces,      // [NF, 3]
    const int*   __restrict__ cidx,       // [B, NC, 2]
    float*       __restrict__ partials)   // [NBLOCK]
{
    // 55,120 + 55,104 + 27,552 + 64 = 137,840 B  <= 160 KiB
    __shared__ h4             s_v[NVV];     // fp16 vertex (x,y,z,pad), byte off = v*8
    __shared__ unsigned int   s_f01[NFF];   // (i0*8) | ((i1*8) << 16)
    __shared__ unsigned short s_f2[NFF];    // i2*8
    __shared__ float          s_red[16];

    const int b   = blockIdx.x;             // x-major dispatch -> XCD b%8
    const int sl  = blockIdx.y;
    const int tid = threadIdx.x;

    // ---- stage vertices: f32 global -> fp16 half4 LDS ----
    const float* vb = vertices + (size_t)b * (NVV * 3);
    for (int v = tid; v < NVV; v += THREADS) {
        const float* p = vb + 3 * v;
        h4 h;
        h.x = (_Float16)p[0];
        h.y = (_Float16)p[1];
        h.z = (_Float16)p[2];
        h.w = (_Float16)0.0f;
        s_v[v] = h;
    }

    // ---- stage faces as PRE-SHIFTED byte offsets (idx*8 < 65536) ----
    for (int f = tid; f < NFF; f += THREADS) {
        int i0 = faces[3 * f + 0];
        int i1 = faces[3 * f + 1];
        int i2 = faces[3 * f + 2];
        s_f01[f] = (unsigned int)(i0 << 3) | ((unsigned int)(i1 << 3) << 16);
        s_f2[f]  = (unsigned short)(i2 << 3);
    }
    __syncthreads();

    // ---- pair loop: 4 pairs per iter via two coalesced int4 loads ----
    float pen = 0.0f;
    const v4i* c4 = (const v4i*)(cidx + ((size_t)b * NCC + (size_t)sl * PAIRS_PER_SLOT) * 2);
    for (int q = tid; q < QHALF; q += THREADS) {
        v4i pA = __builtin_nontemporal_load(c4 + q);            // pairs {2q, 2q+1}
        v4i pB = __builtin_nontemporal_load(c4 + q + QHALF);    // pairs {2(q+QHALF), ...}
        pen += pairPen(s_v, s_f01, s_f2, pA.x, pA.y);
        pen += pairPen(s_v, s_f01, s_f2, pA.z, pA.w);
        pen += pairPen(s_v, s_f01, s_f2, pB.x, pB.y);
        pen += pairPen(s_v, s_f01, s_f2, pB.z, pB.w);
    }

    // ---- block reduction: 16 waves ----
#pragma unroll
    for (int off = 32; off > 0; off >>= 1)
        pen += __shfl_down(pen, off, 64);
    const int lane = tid & 63;
    const int wv   = tid >> 6;
    if (lane == 0) s_red[wv] = pen;
    __syncthreads();
    if (tid == 0) {
        float t = 0.0f;
#pragma unroll
        for (int w = 0; w < 16; ++w) t += s_red[w];
        partials[b * SLOTS + sl] = t;
    }
}

// ---------------- fold 256 partials, apply weight / B ----------------
__global__ __launch_bounds__(256) void fin2_kernel(
    const float* __restrict__ partials,
    const float* __restrict__ weight,
    float*       __restrict__ out)
{
    float s = partials[threadIdx.x];      // NBLOCK == 256
#pragma unroll
    for (int off = 32; off > 0; off >>= 1)
        s += __shfl_down(s, off, 64);
    __shared__ float smem[4];
    const int lane = threadIdx.x & 63;
    const int wv   = threadIdx.x >> 6;
    if (lane == 0) smem[wv] = s;
    __syncthreads();
    if (threadIdx.x == 0)
        out[0] = (smem[0] + smem[1] + smem[2] + smem[3]) * weight[0] * (1.0f / (float)BB);
}

// ---------------- fallback: direct per-pair with atomics (tiny ws) --------
__global__ void init_kernel(float* __restrict__ accum) { accum[0] = 0.0f; }

__global__ __launch_bounds__(256) void pen_direct(
    const float* __restrict__ vertices, const int* __restrict__ faces,
    const int2* __restrict__ cidx, float* __restrict__ accum)
{
    const int i = blockIdx.x * blockDim.x + threadIdx.x;
    float pen = 0.0f;
    if (i < BB * NCC) {
        const int b = i / NCC;
        const int2 pr = cidx[i];
        if (pr.x >= 0) {
            const int f0 = pr.x;
            const int f1 = pr.y < 0 ? 0 : pr.y;
            const float* vb = vertices + (size_t)b * (NVV * 3);
            float3 a0 = loadv3(vb + (size_t)faces[f0*3+0] * 3);
            float3 a1 = loadv3(vb + (size_t)faces[f0*3+1] * 3);
            float3 a2 = loadv3(vb + (size_t)faces[f0*3+2] * 3);
            float3 b0 = loadv3(vb + (size_t)faces[f1*3+0] * 3);
            float3 b1 = loadv3(vb + (size_t)faces[f1*3+1] * 3);
            float3 b2 = loadv3(vb + (size_t)faces[f1*3+2] * 3);
            pen = conePen(a0,a1,a2,b0,b1,b2) + conePen(b0,b1,b2,a0,a1,a2);
        }
    }
#pragma unroll
    for (int off = 32; off > 0; off >>= 1)
        pen += __shfl_down(pen, off, 64);
    __shared__ float smem[4];
    const int lane = threadIdx.x & 63;
    const int wv   = threadIdx.x >> 6;
    if (lane == 0) smem[wv] = pen;
    __syncthreads();
    if (threadIdx.x == 0)
        atomicAdd(accum, smem[0] + smem[1] + smem[2] + smem[3]);
}

__global__ void fin_kernel(const float* __restrict__ accum,
                           const float* __restrict__ weight,
                           float* __restrict__ out)
{
    out[0] = accum[0] * weight[0] * (1.0f / (float)BB);
}

extern "C" void kernel_launch(void* const* d_in, const int* in_sizes, int n_in,
                              void* d_out, int out_size, void* d_ws, size_t ws_size,
                              hipStream_t stream) {
    const float* vertices = (const float*)d_in[4];
    const float* weight   = (const float*)d_in[5];
    const int*   faces    = (const int*)d_in[6];
    const int*   cidx     = (const int*)d_in[7];
    float* out = (float*)d_out;

    if (ws_size >= NBLOCK * sizeof(float)) {
        float* partials = (float*)d_ws;
        fused_kernel<<<dim3(BB, SLOTS), dim3(THREADS), 0, stream>>>(
            vertices, faces, cidx, partials);
        fin2_kernel<<<dim3(1), dim3(256), 0, stream>>>(partials, weight, out);
    } else {
        float* accum = (float*)d_ws;
        const int totalPairs = BB * NCC;
        init_kernel<<<dim3(1), dim3(1), 0, stream>>>(accum);
        pen_direct<<<dim3((totalPairs + 255) / 256), dim3(256), 0, stream>>>(
            vertices, faces, (const int2*)cidx, accum);
        fin_kernel<<<dim3(1), dim3(1), 0, stream>>>(accum, weight, out);
    }
}

// Round 3
// 111.756 us; speedup vs baseline: 1.1284x; 1.1284x over previous
//
#include <hip/hip_runtime.h>

#define SIGMA 0.5f
#define BB 32
#define NVV 6890
#define NFF 13776
#define MAXC 8
#define NCC (NFF * MAXC)                 // 110208 pairs per batch

// fused kernel geometry: one block per (batch, slot); 8 slots per batch.
#define SLOTS 8
#define PAIRS_PER_SLOT (NCC / SLOTS)     // 13776 exactly
#define QHALF (PAIRS_PER_SLOT / 4)       // 3444 exactly (4 pairs per thread-iter)
#define THREADS 1024
#define NBLOCK (BB * SLOTS)              // 256 blocks == 256 CUs

typedef int       v4i __attribute__((ext_vector_type(4)));
typedef _Float16  h4  __attribute__((ext_vector_type(4)));

__device__ __forceinline__ float3 loadv3(const float* __restrict__ p) {
    return make_float3(p[0], p[1], p[2]);
}

// raw-instruction transcendentals (v_sqrt_f32 / v_rcp_f32, ~1 ulp):
// avoids the no-fast-math guarded sqrt expansion and the 12-instr div sequence.
__device__ __forceinline__ float fsqrt(float x) { return __builtin_amdgcn_sqrtf(x); }
__device__ __forceinline__ float frcp(float x)  { return __builtin_amdgcn_rcpf(x); }

// one-sided conic penetration, BRANCHLESS: query verts q0..q2 in field of (c, n)
__device__ __forceinline__ float coneSide(float cx, float cy, float cz,
                                          float nx, float ny, float nz,
                                          float3 q0, float3 q1, float3 q2) {
    float pen = 0.0f;
#pragma unroll
    for (int v = 0; v < 3; ++v) {
        float3 q = (v == 0) ? q0 : ((v == 1) ? q1 : q2);
        float dx = q.x - cx, dy = q.y - cy, dz = q.z - cz;
        float h  = dx * nx + dy * ny + dz * nz;
        float r2 = dx * dx + dy * dy + dz * dz;
        float r  = fsqrt(r2);
        float phi = fmaxf(SIGMA - r, 0.0f);
        float hm  = fminf(h, 0.0f);          // (h<0 ? phi*h*h : 0) == phi*hm*hm
        pen = fmaf(phi * hm, hm, pen);
    }
    return pen;
}

// symmetric penetration for one tri pair (A verts, B verts), f32 math
__device__ __forceinline__ float triPairPen(float3 A0, float3 A1, float3 A2,
                                            float3 B0, float3 B1, float3 B2) {
    const float third = 1.0f / 3.0f;
    // centroids
    float cax = (A0.x + A1.x + A2.x) * third;
    float cay = (A0.y + A1.y + A2.y) * third;
    float caz = (A0.z + A1.z + A2.z) * third;
    float cbx = (B0.x + B1.x + B2.x) * third;
    float cby = (B0.y + B1.y + B2.y) * third;
    float cbz = (B0.z + B1.z + B2.z) * third;
    // normal A (reference formula: n / (|n| + 1e-8), rcp+sqrt raw)
    float e1x = A1.x - A0.x, e1y = A1.y - A0.y, e1z = A1.z - A0.z;
    float e2x = A2.x - A0.x, e2y = A2.y - A0.y, e2z = A2.z - A0.z;
    float nax = e1y * e2z - e1z * e2y;
    float nay = e1z * e2x - e1x * e2z;
    float naz = e1x * e2y - e1y * e2x;
    float inva = frcp(fsqrt(nax * nax + nay * nay + naz * naz) + 1e-8f);
    nax *= inva; nay *= inva; naz *= inva;
    // normal B
    float f1x = B1.x - B0.x, f1y = B1.y - B0.y, f1z = B1.z - B0.z;
    float f2x = B2.x - B0.x, f2y = B2.y - B0.y, f2z = B2.z - B0.z;
    float nbx = f1y * f2z - f1z * f2y;
    float nby = f1z * f2x - f1x * f2z;
    float nbz = f1x * f2y - f1y * f2x;
    float invb = frcp(fsqrt(nbx * nbx + nby * nby + nbz * nbz) + 1e-8f);
    nbx *= invb; nby *= invb; nbz *= invb;

    return coneSide(cax, cay, caz, nax, nay, naz, B0, B1, B2)
         + coneSide(cbx, cby, cbz, nbx, nby, nbz, A0, A1, A2);
}

// load one fp16 vertex by PRE-SHIFTED byte offset (one ds_read_b64)
__device__ __forceinline__ float3 ldsVertB(const h4* __restrict__ sv, unsigned int boff) {
    h4 h = *(const h4*)((const char*)sv + boff);
    return make_float3((float)h.x, (float)h.y, (float)h.z);
}

// fully branchless pair evaluation; invalid (r<0) pairs masked at the end
__device__ __forceinline__ float pairPen(const h4* __restrict__ sv,
                                         const unsigned int*   __restrict__ f01,
                                         const unsigned short* __restrict__ f2,
                                         int r, int it) {
    const int rr = r  < 0 ? 0 : r;        // clamp; result masked below
    const int g  = it < 0 ? 0 : it;       // reference clamps with max(idx,0)
    unsigned int wa  = f01[rr];
    unsigned int wb  = f01[g];
    unsigned int oa2 = f2[rr];            // byte offsets (idx*8)
    unsigned int ob2 = f2[g];
    float3 A0 = ldsVertB(sv, wa & 0xFFFFu);
    float3 A1 = ldsVertB(sv, wa >> 16);
    float3 A2 = ldsVertB(sv, oa2);
    float3 B0 = ldsVertB(sv, wb & 0xFFFFu);
    float3 B1 = ldsVertB(sv, wb >> 16);
    float3 B2 = ldsVertB(sv, ob2);
    float pen = triPairPen(A0, A1, A2, B0, B1, B2);
    return r < 0 ? 0.0f : pen;            // one cndmask, no control flow
}

// ---------------- fused: stage batch verts+faces in LDS, eval pairs --------
__global__ __launch_bounds__(THREADS) void fused_kernel(
    const float* __restrict__ vertices,   // [B, NV, 3]
    const int*   __restrict__ faces,      // [NF, 3]
    const int*   __restrict__ cidx,       // [B, NC, 2]
    float*       __restrict__ partials)   // [NBLOCK]
{
    // 55,120 + 55,104 + 27,552 + 64 = 137,840 B  <= 160 KiB
    __shared__ h4             s_v[NVV];     // fp16 vertex (x,y,z,pad), byte off = v*8
    __shared__ unsigned int   s_f01[NFF];   // (i0*8) | ((i1*8) << 16)
    __shared__ unsigned short s_f2[NFF];    // i2*8
    __shared__ float          s_red[16];

    const int b   = blockIdx.x;             // x-major dispatch -> XCD b%8
    const int sl  = blockIdx.y;
    const int tid = threadIdx.x;

    // ---- stage vertices: f32 global -> fp16 half4 LDS ----
    const float* vb = vertices + (size_t)b * (NVV * 3);
    for (int v = tid; v < NVV; v += THREADS) {
        const float* p = vb + 3 * v;
        h4 h;
        h.x = (_Float16)p[0];
        h.y = (_Float16)p[1];
        h.z = (_Float16)p[2];
        h.w = (_Float16)0.0f;
        s_v[v] = h;
    }

    // ---- stage faces as PRE-SHIFTED byte offsets (idx*8 < 65536) ----
    for (int f = tid; f < NFF; f += THREADS) {
        int i0 = faces[3 * f + 0];
        int i1 = faces[3 * f + 1];
        int i2 = faces[3 * f + 2];
        s_f01[f] = (unsigned int)(i0 << 3) | ((unsigned int)(i1 << 3) << 16);
        s_f2[f]  = (unsigned short)(i2 << 3);
    }
    __syncthreads();

    // ---- pair loop: 4 pairs per iter, independent accumulators ----
    float pen = 0.0f;
    const v4i* c4 = (const v4i*)(cidx + ((size_t)b * NCC + (size_t)sl * PAIRS_PER_SLOT) * 2);
    for (int q = tid; q < QHALF; q += THREADS) {
        v4i pA = __builtin_nontemporal_load(c4 + q);            // pairs {2q, 2q+1}
        v4i pB = __builtin_nontemporal_load(c4 + q + QHALF);
        float p0 = pairPen(s_v, s_f01, s_f2, pA.x, pA.y);
        float p1 = pairPen(s_v, s_f01, s_f2, pA.z, pA.w);
        float p2 = pairPen(s_v, s_f01, s_f2, pB.x, pB.y);
        float p3 = pairPen(s_v, s_f01, s_f2, pB.z, pB.w);
        pen += (p0 + p1) + (p2 + p3);
    }

    // ---- block reduction: 16 waves ----
#pragma unroll
    for (int off = 32; off > 0; off >>= 1)
        pen += __shfl_down(pen, off, 64);
    const int lane = tid & 63;
    const int wv   = tid >> 6;
    if (lane == 0) s_red[wv] = pen;
    __syncthreads();
    if (tid == 0) {
        float t = 0.0f;
#pragma unroll
        for (int w = 0; w < 16; ++w) t += s_red[w];
        partials[b * SLOTS + sl] = t;
    }
}

// ---------------- fold 256 partials, apply weight / B ----------------
__global__ __launch_bounds__(256) void fin2_kernel(
    const float* __restrict__ partials,
    const float* __restrict__ weight,
    float*       __restrict__ out)
{
    float s = partials[threadIdx.x];      // NBLOCK == 256
#pragma unroll
    for (int off = 32; off > 0; off >>= 1)
        s += __shfl_down(s, off, 64);
    __shared__ float smem[4];
    const int lane = threadIdx.x & 63;
    const int wv   = threadIdx.x >> 6;
    if (lane == 0) smem[wv] = s;
    __syncthreads();
    if (threadIdx.x == 0)
        out[0] = (smem[0] + smem[1] + smem[2] + smem[3]) * weight[0] * (1.0f / (float)BB);
}

// ---------------- fallback: direct per-pair with atomics (tiny ws) --------
__global__ void init_kernel(float* __restrict__ accum) { accum[0] = 0.0f; }

__global__ __launch_bounds__(256) void pen_direct(
    const float* __restrict__ vertices, const int* __restrict__ faces,
    const int2* __restrict__ cidx, float* __restrict__ accum)
{
    const int i = blockIdx.x * blockDim.x + threadIdx.x;
    float pen = 0.0f;
    if (i < BB * NCC) {
        const int b = i / NCC;
        const int2 pr = cidx[i];
        if (pr.x >= 0) {
            const int f0 = pr.x;
            const int f1 = pr.y < 0 ? 0 : pr.y;
            const float* vb = vertices + (size_t)b * (NVV * 3);
            float3 a0 = loadv3(vb + (size_t)faces[f0*3+0] * 3);
            float3 a1 = loadv3(vb + (size_t)faces[f0*3+1] * 3);
            float3 a2 = loadv3(vb + (size_t)faces[f0*3+2] * 3);
            float3 b0 = loadv3(vb + (size_t)faces[f1*3+0] * 3);
            float3 b1 = loadv3(vb + (size_t)faces[f1*3+1] * 3);
            float3 b2 = loadv3(vb + (size_t)faces[f1*3+2] * 3);
            pen = triPairPen(a0, a1, a2, b0, b1, b2);
        }
    }
#pragma unroll
    for (int off = 32; off > 0; off >>= 1)
        pen += __shfl_down(pen, off, 64);
    __shared__ float smem[4];
    const int lane = threadIdx.x & 63;
    const int wv   = threadIdx.x >> 6;
    if (lane == 0) smem[wv] = pen;
    __syncthreads();
    if (threadIdx.x == 0)
        atomicAdd(accum, smem[0] + smem[1] + smem[2] + smem[3]);
}

__global__ void fin_kernel(const float* __restrict__ accum,
                           const float* __restrict__ weight,
                           float* __restrict__ out)
{
    out[0] = accum[0] * weight[0] * (1.0f / (float)BB);
}

extern "C" void kernel_launch(void* const* d_in, const int* in_sizes, int n_in,
                              void* d_out, int out_size, void* d_ws, size_t ws_size,
                              hipStream_t stream) {
    const float* vertices = (const float*)d_in[4];
    const float* weight   = (const float*)d_in[5];
    const int*   faces    = (const int*)d_in[6];
    const int*   cidx     = (const int*)d_in[7];
    float* out = (float*)d_out;

    if (ws_size >= NBLOCK * sizeof(float)) {
        float* partials = (float*)d_ws;
        fused_kernel<<<dim3(BB, SLOTS), dim3(THREADS), 0, stream>>>(
            vertices, faces, cidx, partials);
        fin2_kernel<<<dim3(1), dim3(256), 0, stream>>>(partials, weight, out);
    } else {
        float* accum = (float*)d_ws;
        const int totalPairs = BB * NCC;
        init_kernel<<<dim3(1), dim3(1), 0, stream>>>(accum);
        pen_direct<<<dim3((totalPairs + 255) / 256), dim3(256), 0, stream>>>(
            vertices, faces, (const int2*)cidx, accum);
        fin_kernel<<<dim3(1), dim3(1), 0, stream>>>(accum, weight, out);
    }
}